// Round 2
// baseline (4134.728 us; speedup 1.0000x reference)
//
#include <hip/hip_runtime.h>
#include <math.h>

#define N_PIX 3136
#define C_DIM 192
#define HID_DIM 384
#define BATCH 4
#define KNN 9
#define EPS_BN 1e-5f

// ---------------- workspace layout (float elements) ----------------
static const size_t OFF_H   = 0;
static const size_t OFF_SQ  = OFF_H  + (size_t)12544 * 192;
static const size_t OFF_P   = OFF_SQ + 12544;
static const size_t OFF_Q   = OFF_P  + (size_t)12544 * 384;
static const size_t OFF_WC  = OFF_Q  + (size_t)12544 * 384;
static const size_t OFF_CST = OFF_WC + (size_t)768 * 192;
static const size_t OFF_IDX = OFF_CST + 1536;            // int region (12544*9)
static const size_t OFF_PL  = OFF_IDX + 112896;          // u64 region (12544*4*9), float-offset

// ---------------- prep: Wcomb + BN scale/shift ----------------
__global__ void k_prep(const float* __restrict__ gcn_w,
                       const float* __restrict__ bn1_g, const float* __restrict__ bn1_b,
                       const float* __restrict__ bn1_m, const float* __restrict__ bn1_v,
                       const float* __restrict__ bng_g, const float* __restrict__ bng_b,
                       const float* __restrict__ bng_m, const float* __restrict__ bng_v,
                       const float* __restrict__ bn2_g, const float* __restrict__ bn2_b,
                       const float* __restrict__ bn2_m, const float* __restrict__ bn2_v,
                       float* __restrict__ wc, float* __restrict__ cst)
{
    int t = blockIdx.x * 256 + threadIdx.x;
    if (t < 768 * 192) {
        int o = t / 192, c = t % 192;
        float v;
        if (o < 384) v = gcn_w[o * 384 + c] - gcn_w[o * 384 + 192 + c];
        else         v = gcn_w[(o - 384) * 384 + 192 + c];
        wc[t] = v;
    }
    int u = t - 768 * 192;
    if (u >= 0 && u < 768) {
        if (u < 192) {
            float s = bn1_g[u] / sqrtf(bn1_v[u] + EPS_BN);
            cst[u] = s; cst[192 + u] = bn1_b[u] - bn1_m[u] * s;
        } else if (u < 576) {
            int ch = u - 192;
            float s = bng_g[ch] / sqrtf(bng_v[ch] + EPS_BN);
            cst[384 + ch] = s; cst[768 + ch] = bng_b[ch] - bng_m[ch] * s;
        } else {
            int ch = u - 576;
            float s = bn2_g[ch] / sqrtf(bn2_v[ch] + EPS_BN);
            cst[1152 + ch] = s; cst[1344 + ch] = bn2_b[ch] - bn2_m[ch] * s;
        }
    }
}

// ---------------- K1: h = bn1(xf @ fc1_w^T + fc1_b) ----------------
__global__ __launch_bounds__(256) void k1_fc1_bn1(
    const float* __restrict__ x, const float* __restrict__ w,
    const float* __restrict__ bias, const float* __restrict__ cst,
    float* __restrict__ h)
{
    __shared__ float As[32][64];
    __shared__ float Bs[32][64];
    int bx = blockIdx.x;
    int o0 = blockIdx.y * 64;
    int b  = bx / 49;
    int n0 = (bx % 49) * 64;
    const float* xb = x + (size_t)b * C_DIM * N_PIX;
    int t = threadIdx.x;
    int tx = t & 15, ty = t >> 4;
    float acc[4][4] = {};
    for (int kc = 0; kc < 6; ++kc) {
        #pragma unroll
        for (int p = 0; p < 2; ++p) {
            int idx = t + p * 256;
            int kk = idx >> 4, j4 = idx & 15;
            float4 v = *reinterpret_cast<const float4*>(xb + (size_t)(kc * 32 + kk) * N_PIX + n0 + j4 * 4);
            *reinterpret_cast<float4*>(&As[kk][j4 * 4]) = v;
        }
        #pragma unroll
        for (int p = 0; p < 2; ++p) {
            int idx = t + p * 256;
            int oo = idx >> 3, c4 = idx & 7;
            float4 v = *reinterpret_cast<const float4*>(w + (size_t)(o0 + oo) * C_DIM + kc * 32 + c4 * 4);
            Bs[c4 * 4 + 0][oo] = v.x; Bs[c4 * 4 + 1][oo] = v.y;
            Bs[c4 * 4 + 2][oo] = v.z; Bs[c4 * 4 + 3][oo] = v.w;
        }
        __syncthreads();
        #pragma unroll
        for (int kk = 0; kk < 32; ++kk) {
            float4 av = *reinterpret_cast<const float4*>(&As[kk][ty * 4]);
            float4 bv = *reinterpret_cast<const float4*>(&Bs[kk][tx * 4]);
            float a[4] = {av.x, av.y, av.z, av.w};
            float bb[4] = {bv.x, bv.y, bv.z, bv.w};
            #pragma unroll
            for (int i = 0; i < 4; ++i)
                #pragma unroll
                for (int j = 0; j < 4; ++j) acc[i][j] += a[i] * bb[j];
        }
        __syncthreads();
    }
    #pragma unroll
    for (int i = 0; i < 4; ++i) {
        int n = n0 + ty * 4 + i;
        size_t r = (size_t)b * N_PIX + n;
        float vals[4];
        #pragma unroll
        for (int j = 0; j < 4; ++j) {
            int o = o0 + tx * 4 + j;
            vals[j] = (acc[i][j] + bias[o]) * cst[o] + cst[192 + o];
        }
        *reinterpret_cast<float4*>(h + r * C_DIM + o0 + tx * 4) =
            make_float4(vals[0], vals[1], vals[2], vals[3]);
    }
}

// ---------------- K1b: sq[r] = sum_c h[r][c]^2 ----------------
__global__ __launch_bounds__(256) void k_sq(const float* __restrict__ h, float* __restrict__ sq)
{
    int r = blockIdx.x * 256 + threadIdx.x;
    const float* hr = h + (size_t)r * C_DIM;
    float s = 0.f;
    #pragma unroll
    for (int c = 0; c < C_DIM; c += 4) {
        float4 v = *reinterpret_cast<const float4*>(hr + c);
        s += v.x * v.x + v.y * v.y + v.z * v.z + v.w * v.w;
    }
    sq[r] = s;
}

// ---------------- K2: P = h@Wd^T + gcn_b ; Q = h@W2^T ----------------
__global__ __launch_bounds__(256) void k2_pq(
    const float* __restrict__ h, const float* __restrict__ wc,
    const float* __restrict__ gcnb, float* __restrict__ P, float* __restrict__ Q)
{
    __shared__ float As[32][64];
    __shared__ float Bs[32][64];
    int r0 = blockIdx.x * 64;
    int o0 = blockIdx.y * 64;
    int t = threadIdx.x;
    int tx = t & 15, ty = t >> 4;
    float acc[4][4] = {};
    for (int kc = 0; kc < 6; ++kc) {
        #pragma unroll
        for (int p = 0; p < 2; ++p) {
            int idx = t + p * 256;
            int j = idx >> 3, c4 = idx & 7;
            float4 v = *reinterpret_cast<const float4*>(h + (size_t)(r0 + j) * C_DIM + kc * 32 + c4 * 4);
            As[c4 * 4 + 0][j] = v.x; As[c4 * 4 + 1][j] = v.y;
            As[c4 * 4 + 2][j] = v.z; As[c4 * 4 + 3][j] = v.w;
        }
        #pragma unroll
        for (int p = 0; p < 2; ++p) {
            int idx = t + p * 256;
            int oo = idx >> 3, c4 = idx & 7;
            float4 v = *reinterpret_cast<const float4*>(wc + (size_t)(o0 + oo) * C_DIM + kc * 32 + c4 * 4);
            Bs[c4 * 4 + 0][oo] = v.x; Bs[c4 * 4 + 1][oo] = v.y;
            Bs[c4 * 4 + 2][oo] = v.z; Bs[c4 * 4 + 3][oo] = v.w;
        }
        __syncthreads();
        #pragma unroll
        for (int kk = 0; kk < 32; ++kk) {
            float4 av = *reinterpret_cast<const float4*>(&As[kk][ty * 4]);
            float4 bv = *reinterpret_cast<const float4*>(&Bs[kk][tx * 4]);
            float a[4] = {av.x, av.y, av.z, av.w};
            float bb[4] = {bv.x, bv.y, bv.z, bv.w};
            #pragma unroll
            for (int i = 0; i < 4; ++i)
                #pragma unroll
                for (int j = 0; j < 4; ++j) acc[i][j] += a[i] * bb[j];
        }
        __syncthreads();
    }
    bool isP = (o0 < HID_DIM);
    #pragma unroll
    for (int i = 0; i < 4; ++i) {
        size_t r = (size_t)(r0 + ty * 4 + i);
        int ocb = o0 + tx * 4;
        float vals[4];
        #pragma unroll
        for (int j = 0; j < 4; ++j)
            vals[j] = acc[i][j] + (isP ? gcnb[ocb + j] : 0.0f);
        float4 vv = make_float4(vals[0], vals[1], vals[2], vals[3]);
        if (isP) *reinterpret_cast<float4*>(P + r * HID_DIM + ocb) = vv;
        else     *reinterpret_cast<float4*>(Q + r * HID_DIM + (ocb - HID_DIM)) = vv;
    }
}

// ---------------- K3: fused pairwise-dist + partial top-9 ----------------
// grid: 4b * 49strip * 4mchunk = 784 blocks, 512 threads.
// LDS row-major padded stride 68; m strided (tx+16j) -> 2-way reads (free);
// A reads broadcast; staging = direct float4 copies (conflict-free).
#define S_LD 68
__global__ __launch_bounds__(512, 4) void k3_knn(
    const float* __restrict__ h, const float* __restrict__ sq,
    unsigned long long* __restrict__ pl)
{
    __shared__ float As[64 * S_LD];    // 17.4 KB
    __shared__ float Bs[112 * S_LD];   // 30.5 KB
    int bx = blockIdx.x;
    int b     = bx / 196;
    int rem   = bx % 196;
    int strip = rem >> 2;
    int mc    = rem & 3;
    int n0 = strip * 64;
    const float* hb  = h  + (size_t)b * N_PIX * C_DIM;
    const float* sqb = sq + (size_t)b * N_PIX;
    int t = threadIdx.x;
    int tx = t & 15, ty = t >> 4;          // ty 0..31

    unsigned long long cand[2][KNN];
    #pragma unroll
    for (int i = 0; i < 2; ++i)
        #pragma unroll
        for (int q = 0; q < KNN; ++q) cand[i][q] = ~0ull;

    float sqn[2] = { sqb[n0 + ty * 2], sqb[n0 + ty * 2 + 1] };

    for (int mt = 0; mt < 7; ++mt) {
        int m0 = mc * 784 + mt * 112;
        float acc[2][7] = {};
        for (int kh = 0; kh < 3; ++kh) {           // k chunks of 64
            __syncthreads();
            for (int f = t; f < 1024 + 1792; f += 512) {
                int isB = (f >= 1024);
                int fr  = isB ? f - 1024 : f;
                int row = fr >> 4, k4 = fr & 15;
                int grow = isB ? (m0 + row) : (n0 + row);
                float4 v = *reinterpret_cast<const float4*>(hb + (size_t)grow * C_DIM + kh * 64 + k4 * 4);
                float* dst = (isB ? Bs : As) + row * S_LD + k4 * 4;
                *reinterpret_cast<float4*>(dst) = v;
            }
            __syncthreads();
            #pragma unroll
            for (int k4 = 0; k4 < 16; ++k4) {
                float4 a0 = *reinterpret_cast<const float4*>(As + (ty * 2 + 0) * S_LD + k4 * 4);
                float4 a1 = *reinterpret_cast<const float4*>(As + (ty * 2 + 1) * S_LD + k4 * 4);
                #pragma unroll
                for (int j = 0; j < 7; ++j) {
                    float4 bv = *reinterpret_cast<const float4*>(Bs + (tx + 16 * j) * S_LD + k4 * 4);
                    acc[0][j] += a0.x * bv.x + a0.y * bv.y + a0.z * bv.z + a0.w * bv.w;
                    acc[1][j] += a1.x * bv.x + a1.y * bv.y + a1.z * bv.z + a1.w * bv.w;
                }
            }
        }
        #pragma unroll
        for (int j = 0; j < 7; ++j) {
            int m = m0 + tx + 16 * j;
            float sqm = sqb[m];
            #pragma unroll
            for (int i = 0; i < 2; ++i) {
                float dist = (sqn[i] - 2.0f * acc[i][j]) + sqm;
                unsigned u = __float_as_uint(dist);
                u = (u & 0x80000000u) ? ~u : (u | 0x80000000u);
                unsigned long long key = ((unsigned long long)u << 32) | (unsigned)m;
                if (key < cand[i][KNN - 1]) {
                    cand[i][KNN - 1] = key;
                    #pragma unroll
                    for (int q = KNN - 1; q > 0; --q) {
                        unsigned long long lo = cand[i][q - 1], hi = cand[i][q];
                        if (hi < lo) { cand[i][q - 1] = hi; cand[i][q] = lo; }
                    }
                }
            }
        }
    }
    // 16-lane merge per row, write sorted partial list for this m-chunk
    #pragma unroll
    for (int i = 0; i < 2; ++i) {
        int n = n0 + ty * 2 + i;
        size_t rowg = (size_t)b * N_PIX + n;
        for (int r = 0; r < KNN; ++r) {
            unsigned long long my = cand[i][0];
            unsigned long long g = my;
            #pragma unroll
            for (int s = 1; s < 16; s <<= 1) {
                unsigned long long o = __shfl_xor(g, s);
                if (o < g) g = o;
            }
            if (g == my) {
                #pragma unroll
                for (int q = 0; q < KNN - 1; ++q) cand[i][q] = cand[i][q + 1];
                cand[i][KNN - 1] = ~0ull;
            }
            if (tx == 0)
                pl[(rowg * 4 + mc) * KNN + r] = g;
        }
    }
}

// ---------------- K3b: merge 4 sorted partial lists -> final idx ----------------
__global__ __launch_bounds__(256) void k3b_merge(
    const unsigned long long* __restrict__ pl, int* __restrict__ idxout)
{
    int r = blockIdx.x * 256 + threadIdx.x;   // 12544 rows
    const unsigned long long* base = pl + (size_t)r * 36;
    unsigned long long list[KNN];
    #pragma unroll
    for (int q = 0; q < KNN; ++q) list[q] = ~0ull;
    #pragma unroll
    for (int c = 0; c < 36; ++c) {
        unsigned long long k = base[c];
        if (k < list[KNN - 1]) {
            list[KNN - 1] = k;
            #pragma unroll
            for (int q = KNN - 1; q > 0; --q) {
                unsigned long long lo = list[q - 1], hi = list[q];
                if (hi < lo) { list[q - 1] = hi; list[q] = lo; }
            }
        }
    }
    #pragma unroll
    for (int q = 0; q < KNN; ++q)
        idxout[(size_t)r * KNN + q] = (int)(list[q] & 0xffffffffu);
}

// ---------------- K4: g = gelu(bn_g(P + max_k Q[idx[k]])) (in-place into P) ----------------
__global__ __launch_bounds__(384) void k4_agg(
    float* __restrict__ P, const float* __restrict__ Q,
    const int* __restrict__ idx, const float* __restrict__ cst)
{
    int blk = blockIdx.x;
    int b = blk / N_PIX;
    size_t row = (size_t)blk;
    const int* id = idx + row * KNN;
    int o = threadIdx.x;
    const float* Qb = Q + (size_t)b * N_PIX * HID_DIM;
    float v = -INFINITY;
    #pragma unroll
    for (int k = 0; k < KNN; ++k)
        v = fmaxf(v, Qb[(size_t)id[k] * HID_DIM + o]);
    float gp = P[row * HID_DIM + o] + v;
    float y = gp * cst[384 + o] + cst[768 + o];
    float ge = 0.5f * y * (1.0f + erff(y * 0.70710678118654752f));
    P[row * HID_DIM + o] = ge;
}

// ---------------- K5: out = bn2(g @ fc2_w^T + fc2_b) + x ----------------
__global__ __launch_bounds__(256) void k5_fc2_bn2(
    const float* __restrict__ g, const float* __restrict__ w,
    const float* __restrict__ bias, const float* __restrict__ cst,
    const float* __restrict__ x, float* __restrict__ out)
{
    __shared__ float As[32][64];
    __shared__ float Bs[32][64];
    int bx = blockIdx.x;
    int c0 = blockIdx.y * 64;
    int b  = bx / 49;
    int n0 = (bx % 49) * 64;
    int r0 = bx * 64;
    int t = threadIdx.x;
    int tx = t & 15, ty = t >> 4;
    float acc[4][4] = {};
    for (int kc = 0; kc < 12; ++kc) {
        #pragma unroll
        for (int p = 0; p < 2; ++p) {
            int idx = t + p * 256;
            int j = idx >> 3, c4 = idx & 7;
            float4 v = *reinterpret_cast<const float4*>(g + (size_t)(r0 + j) * HID_DIM + kc * 32 + c4 * 4);
            As[c4 * 4 + 0][j] = v.x; As[c4 * 4 + 1][j] = v.y;
            As[c4 * 4 + 2][j] = v.z; As[c4 * 4 + 3][j] = v.w;
        }
        #pragma unroll
        for (int p = 0; p < 2; ++p) {
            int idx = t + p * 256;
            int oo = idx >> 3, c4 = idx & 7;
            float4 v = *reinterpret_cast<const float4*>(w + (size_t)(c0 + oo) * HID_DIM + kc * 32 + c4 * 4);
            Bs[c4 * 4 + 0][oo] = v.x; Bs[c4 * 4 + 1][oo] = v.y;
            Bs[c4 * 4 + 2][oo] = v.z; Bs[c4 * 4 + 3][oo] = v.w;
        }
        __syncthreads();
        #pragma unroll
        for (int kk = 0; kk < 32; ++kk) {
            float4 av = *reinterpret_cast<const float4*>(&As[kk][ty * 4]);
            float4 bv = *reinterpret_cast<const float4*>(&Bs[kk][tx * 4]);
            float a[4] = {av.x, av.y, av.z, av.w};
            float bb[4] = {bv.x, bv.y, bv.z, bv.w};
            #pragma unroll
            for (int i = 0; i < 4; ++i)
                #pragma unroll
                for (int j = 0; j < 4; ++j) acc[i][j] += a[i] * bb[j];
        }
        __syncthreads();
    }
    #pragma unroll
    for (int i = 0; i < 4; ++i) {
        int n = n0 + ty * 4 + i;
        #pragma unroll
        for (int j = 0; j < 4; ++j) {
            int c = c0 + tx * 4 + j;
            size_t a = (size_t)b * C_DIM * N_PIX + (size_t)c * N_PIX + n;
            float y = (acc[i][j] + bias[c]) * cst[1152 + c] + cst[1344 + c] + x[a];
            out[a] = y;
        }
    }
}

extern "C" void kernel_launch(void* const* d_in, const int* in_sizes, int n_in,
                              void* d_out, int out_size, void* d_ws, size_t ws_size,
                              hipStream_t stream)
{
    const float* x      = (const float*)d_in[0];
    const float* fc1_w  = (const float*)d_in[1];
    const float* fc1_b  = (const float*)d_in[2];
    const float* bn1_g  = (const float*)d_in[3];
    const float* bn1_b  = (const float*)d_in[4];
    const float* bn1_m  = (const float*)d_in[5];
    const float* bn1_v  = (const float*)d_in[6];
    const float* gcn_w  = (const float*)d_in[7];
    const float* gcn_b  = (const float*)d_in[8];
    const float* bng_g  = (const float*)d_in[9];
    const float* bng_b  = (const float*)d_in[10];
    const float* bng_m  = (const float*)d_in[11];
    const float* bng_v  = (const float*)d_in[12];
    const float* fc2_w  = (const float*)d_in[13];
    const float* fc2_b  = (const float*)d_in[14];
    const float* bn2_g  = (const float*)d_in[15];
    const float* bn2_b  = (const float*)d_in[16];
    const float* bn2_m  = (const float*)d_in[17];
    const float* bn2_v  = (const float*)d_in[18];
    float* out = (float*)d_out;

    float* ws  = (float*)d_ws;
    float* h   = ws + OFF_H;
    float* sq  = ws + OFF_SQ;
    float* P   = ws + OFF_P;
    float* Q   = ws + OFF_Q;
    float* wc  = ws + OFF_WC;
    float* cst = ws + OFF_CST;
    int*   idx = (int*)(ws + OFF_IDX);
    unsigned long long* pl = (unsigned long long*)(ws + OFF_PL);

    k_prep<<<579, 256, 0, stream>>>(gcn_w, bn1_g, bn1_b, bn1_m, bn1_v,
                                    bng_g, bng_b, bng_m, bng_v,
                                    bn2_g, bn2_b, bn2_m, bn2_v, wc, cst);
    k1_fc1_bn1<<<dim3(196, 3), 256, 0, stream>>>(x, fc1_w, fc1_b, cst, h);
    k_sq<<<49, 256, 0, stream>>>(h, sq);
    k2_pq<<<dim3(196, 12), 256, 0, stream>>>(h, wc, gcn_b, P, Q);
    k3_knn<<<784, 512, 0, stream>>>(h, sq, pl);
    k3b_merge<<<49, 256, 0, stream>>>(pl, idx);
    k4_agg<<<12544, 384, 0, stream>>>(P, Q, idx, cst);
    k5_fc2_bn2<<<dim3(196, 3), 256, 0, stream>>>(P, fc2_w, fc2_b, cst, x, out);
}

// Round 4
// 895.165 us; speedup vs baseline: 4.6190x; 4.6190x over previous
//
#include <hip/hip_runtime.h>
#include <math.h>

#define N_PIX 3136
#define C_DIM 192
#define HID_DIM 384
#define BATCH 4
#define KNN 9
#define EPS_BN 1e-5f

// ---------------- workspace layout (float elements) ----------------
static const size_t OFF_H   = 0;
static const size_t OFF_SQ  = OFF_H  + (size_t)12544 * 192;
static const size_t OFF_P   = OFF_SQ + 12544;
static const size_t OFF_Q   = OFF_P  + (size_t)12544 * 384;
static const size_t OFF_WC  = OFF_Q  + (size_t)12544 * 384;
static const size_t OFF_CST = OFF_WC + (size_t)768 * 192;
static const size_t OFF_IDX = OFF_CST + 1536;            // int region (12544*9)
static const size_t OFF_PL  = OFF_IDX + 112896;          // u64 region (12544*7*9)

// ---------------- prep: Wcomb + BN scale/shift ----------------
__global__ void k_prep(const float* __restrict__ gcn_w,
                       const float* __restrict__ bn1_g, const float* __restrict__ bn1_b,
                       const float* __restrict__ bn1_m, const float* __restrict__ bn1_v,
                       const float* __restrict__ bng_g, const float* __restrict__ bng_b,
                       const float* __restrict__ bng_m, const float* __restrict__ bng_v,
                       const float* __restrict__ bn2_g, const float* __restrict__ bn2_b,
                       const float* __restrict__ bn2_m, const float* __restrict__ bn2_v,
                       float* __restrict__ wc, float* __restrict__ cst)
{
    int t = blockIdx.x * 256 + threadIdx.x;
    if (t < 768 * 192) {
        int o = t / 192, c = t % 192;
        float v;
        if (o < 384) v = gcn_w[o * 384 + c] - gcn_w[o * 384 + 192 + c];
        else         v = gcn_w[(o - 384) * 384 + 192 + c];
        wc[t] = v;
    }
    int u = t - 768 * 192;
    if (u >= 0 && u < 768) {
        if (u < 192) {
            float s = bn1_g[u] / sqrtf(bn1_v[u] + EPS_BN);
            cst[u] = s; cst[192 + u] = bn1_b[u] - bn1_m[u] * s;
        } else if (u < 576) {
            int ch = u - 192;
            float s = bng_g[ch] / sqrtf(bng_v[ch] + EPS_BN);
            cst[384 + ch] = s; cst[768 + ch] = bng_b[ch] - bng_m[ch] * s;
        } else {
            int ch = u - 576;
            float s = bn2_g[ch] / sqrtf(bn2_v[ch] + EPS_BN);
            cst[1152 + ch] = s; cst[1344 + ch] = bn2_b[ch] - bn2_m[ch] * s;
        }
    }
}

// ---------------- K1: h = bn1(xf @ fc1_w^T + fc1_b) ----------------
__global__ __launch_bounds__(256) void k1_fc1_bn1(
    const float* __restrict__ x, const float* __restrict__ w,
    const float* __restrict__ bias, const float* __restrict__ cst,
    float* __restrict__ h)
{
    __shared__ float As[32][64];
    __shared__ float Bs[32][64];
    int bx = blockIdx.x;
    int o0 = blockIdx.y * 64;
    int b  = bx / 49;
    int n0 = (bx % 49) * 64;
    const float* xb = x + (size_t)b * C_DIM * N_PIX;
    int t = threadIdx.x;
    int tx = t & 15, ty = t >> 4;
    float acc[4][4] = {};
    for (int kc = 0; kc < 6; ++kc) {
        #pragma unroll
        for (int p = 0; p < 2; ++p) {
            int idx = t + p * 256;
            int kk = idx >> 4, j4 = idx & 15;
            float4 v = *reinterpret_cast<const float4*>(xb + (size_t)(kc * 32 + kk) * N_PIX + n0 + j4 * 4);
            *reinterpret_cast<float4*>(&As[kk][j4 * 4]) = v;
        }
        #pragma unroll
        for (int p = 0; p < 2; ++p) {
            int idx = t + p * 256;
            int oo = idx >> 3, c4 = idx & 7;
            float4 v = *reinterpret_cast<const float4*>(w + (size_t)(o0 + oo) * C_DIM + kc * 32 + c4 * 4);
            Bs[c4 * 4 + 0][oo] = v.x; Bs[c4 * 4 + 1][oo] = v.y;
            Bs[c4 * 4 + 2][oo] = v.z; Bs[c4 * 4 + 3][oo] = v.w;
        }
        __syncthreads();
        #pragma unroll
        for (int kk = 0; kk < 32; ++kk) {
            float4 av = *reinterpret_cast<const float4*>(&As[kk][ty * 4]);
            float4 bv = *reinterpret_cast<const float4*>(&Bs[kk][tx * 4]);
            float a[4] = {av.x, av.y, av.z, av.w};
            float bb[4] = {bv.x, bv.y, bv.z, bv.w};
            #pragma unroll
            for (int i = 0; i < 4; ++i)
                #pragma unroll
                for (int j = 0; j < 4; ++j) acc[i][j] += a[i] * bb[j];
        }
        __syncthreads();
    }
    #pragma unroll
    for (int i = 0; i < 4; ++i) {
        int n = n0 + ty * 4 + i;
        size_t r = (size_t)b * N_PIX + n;
        float vals[4];
        #pragma unroll
        for (int j = 0; j < 4; ++j) {
            int o = o0 + tx * 4 + j;
            vals[j] = (acc[i][j] + bias[o]) * cst[o] + cst[192 + o];
        }
        *reinterpret_cast<float4*>(h + r * C_DIM + o0 + tx * 4) =
            make_float4(vals[0], vals[1], vals[2], vals[3]);
    }
}

// ---------------- K1b: sq[r] = sum_c h[r][c]^2 ----------------
__global__ __launch_bounds__(256) void k_sq(const float* __restrict__ h, float* __restrict__ sq)
{
    int r = blockIdx.x * 256 + threadIdx.x;
    const float* hr = h + (size_t)r * C_DIM;
    float s = 0.f;
    #pragma unroll
    for (int c = 0; c < C_DIM; c += 4) {
        float4 v = *reinterpret_cast<const float4*>(hr + c);
        s += v.x * v.x + v.y * v.y + v.z * v.z + v.w * v.w;
    }
    sq[r] = s;
}

// ---------------- K2: P = h@Wd^T + gcn_b ; Q = h@W2^T ----------------
__global__ __launch_bounds__(256) void k2_pq(
    const float* __restrict__ h, const float* __restrict__ wc,
    const float* __restrict__ gcnb, float* __restrict__ P, float* __restrict__ Q)
{
    __shared__ float As[32][64];
    __shared__ float Bs[32][64];
    int r0 = blockIdx.x * 64;
    int o0 = blockIdx.y * 64;
    int t = threadIdx.x;
    int tx = t & 15, ty = t >> 4;
    float acc[4][4] = {};
    for (int kc = 0; kc < 6; ++kc) {
        #pragma unroll
        for (int p = 0; p < 2; ++p) {
            int idx = t + p * 256;
            int j = idx >> 3, c4 = idx & 7;
            float4 v = *reinterpret_cast<const float4*>(h + (size_t)(r0 + j) * C_DIM + kc * 32 + c4 * 4);
            As[c4 * 4 + 0][j] = v.x; As[c4 * 4 + 1][j] = v.y;
            As[c4 * 4 + 2][j] = v.z; As[c4 * 4 + 3][j] = v.w;
        }
        #pragma unroll
        for (int p = 0; p < 2; ++p) {
            int idx = t + p * 256;
            int oo = idx >> 3, c4 = idx & 7;
            float4 v = *reinterpret_cast<const float4*>(wc + (size_t)(o0 + oo) * C_DIM + kc * 32 + c4 * 4);
            Bs[c4 * 4 + 0][oo] = v.x; Bs[c4 * 4 + 1][oo] = v.y;
            Bs[c4 * 4 + 2][oo] = v.z; Bs[c4 * 4 + 3][oo] = v.w;
        }
        __syncthreads();
        #pragma unroll
        for (int kk = 0; kk < 32; ++kk) {
            float4 av = *reinterpret_cast<const float4*>(&As[kk][ty * 4]);
            float4 bv = *reinterpret_cast<const float4*>(&Bs[kk][tx * 4]);
            float a[4] = {av.x, av.y, av.z, av.w};
            float bb[4] = {bv.x, bv.y, bv.z, bv.w};
            #pragma unroll
            for (int i = 0; i < 4; ++i)
                #pragma unroll
                for (int j = 0; j < 4; ++j) acc[i][j] += a[i] * bb[j];
        }
        __syncthreads();
    }
    bool isP = (o0 < HID_DIM);
    #pragma unroll
    for (int i = 0; i < 4; ++i) {
        size_t r = (size_t)(r0 + ty * 4 + i);
        int ocb = o0 + tx * 4;
        float vals[4];
        #pragma unroll
        for (int j = 0; j < 4; ++j)
            vals[j] = acc[i][j] + (isP ? gcnb[ocb + j] : 0.0f);
        float4 vv = make_float4(vals[0], vals[1], vals[2], vals[3]);
        if (isP) *reinterpret_cast<float4*>(P + r * HID_DIM + ocb) = vv;
        else     *reinterpret_cast<float4*>(Q + r * HID_DIM + (ocb - HID_DIM)) = vv;
    }
}

// ---------------- K3: fused pairwise-dist + partial top-9 ----------------
// grid: 4b * 49strip * 7mchunk = 1372 blocks, 256 threads.
// [32][64] k-major LDS tiles with XOR block-swizzle:
//   addr(k,col) = k*64 + 4*(((col>>2) ^ (k>>2)) & 15) + (col&3)
// -> staging scalar writes 2-way (free), inner b128 reads aligned & 2-way/broadcast.
__global__ __launch_bounds__(256) void k3_knn(
    const float* __restrict__ h, const float* __restrict__ sq,
    unsigned long long* __restrict__ pl)
{
    __shared__ float As[32 * 64];
    __shared__ float Bs[32 * 64];
    int bx    = blockIdx.x;
    int b     = bx / 343;            // 343 = 49*7
    int rem   = bx % 343;
    int strip = rem / 7;
    int mc    = rem % 7;
    int n0 = strip * 64;
    const float* hb  = h  + (size_t)b * N_PIX * C_DIM;
    const float* sqb = sq + (size_t)b * N_PIX;
    int t = threadIdx.x;
    int tx = t & 15, ty = t >> 4;

    unsigned long long cand[4][KNN];
    #pragma unroll
    for (int i = 0; i < 4; ++i)
        #pragma unroll
        for (int q = 0; q < KNN; ++q) cand[i][q] = ~0ull;

    float sqn[4];
    #pragma unroll
    for (int i = 0; i < 4; ++i) sqn[i] = sqb[n0 + ty * 4 + i];

    for (int mt = 0; mt < 7; ++mt) {
        int m0 = mc * 448 + mt * 64;
        float acc[4][4] = {};
        for (int kc = 0; kc < 6; ++kc) {
            __syncthreads();
            #pragma unroll
            for (int p = 0; p < 2; ++p) {
                int idx = t + p * 256;
                int col = idx >> 3, c4 = idx & 7;
                float4 va = *reinterpret_cast<const float4*>(hb + (size_t)(n0 + col) * C_DIM + kc * 32 + c4 * 4);
                float4 vb = *reinterpret_cast<const float4*>(hb + (size_t)(m0 + col) * C_DIM + kc * 32 + c4 * 4);
                float a_[4] = {va.x, va.y, va.z, va.w};
                float b_[4] = {vb.x, vb.y, vb.z, vb.w};
                #pragma unroll
                for (int r = 0; r < 4; ++r) {
                    int k = c4 * 4 + r;
                    int sw = k * 64 + 4 * (((col >> 2) ^ c4) & 15) + (col & 3);
                    As[sw] = a_[r];
                    Bs[sw] = b_[r];
                }
            }
            __syncthreads();
            #pragma unroll
            for (int kk = 0; kk < 32; ++kk) {
                int f = (kk >> 2) & 15;
                float4 av = *reinterpret_cast<const float4*>(&As[kk * 64 + 4 * (ty ^ f)]);
                float4 bv = *reinterpret_cast<const float4*>(&Bs[kk * 64 + 4 * (tx ^ f)]);
                float a[4] = {av.x, av.y, av.z, av.w};
                float bb[4] = {bv.x, bv.y, bv.z, bv.w};
                #pragma unroll
                for (int i = 0; i < 4; ++i)
                    #pragma unroll
                    for (int j = 0; j < 4; ++j) acc[i][j] += a[i] * bb[j];
            }
        }
        // top-k update: dist = (sq_n - 2*dot) + sq_m (same form as reference)
        #pragma unroll
        for (int j = 0; j < 4; ++j) {
            int m = m0 + tx * 4 + j;
            float sqm = sqb[m];
            #pragma unroll
            for (int i = 0; i < 4; ++i) {
                float dist = (sqn[i] - 2.0f * acc[i][j]) + sqm;
                unsigned u = __float_as_uint(dist);
                u = (u & 0x80000000u) ? ~u : (u | 0x80000000u);
                unsigned long long key = ((unsigned long long)u << 32) | (unsigned)m;
                if (key < cand[i][KNN - 1]) {
                    cand[i][KNN - 1] = key;
                    #pragma unroll
                    for (int q = KNN - 1; q > 0; --q) {
                        unsigned long long lo = cand[i][q - 1], hi = cand[i][q];
                        if (hi < lo) { cand[i][q - 1] = hi; cand[i][q] = lo; }
                    }
                }
            }
        }
    }
    // 16-lane merge per row, write sorted partial list for this m-chunk
    #pragma unroll
    for (int i = 0; i < 4; ++i) {
        int n = n0 + ty * 4 + i;
        size_t rowg = (size_t)b * N_PIX + n;
        for (int r = 0; r < KNN; ++r) {
            unsigned long long my = cand[i][0];
            unsigned long long g = my;
            #pragma unroll
            for (int s = 1; s < 16; s <<= 1) {
                unsigned long long o = __shfl_xor(g, s);
                if (o < g) g = o;
            }
            if (g == my) {
                #pragma unroll
                for (int q = 0; q < KNN - 1; ++q) cand[i][q] = cand[i][q + 1];
                cand[i][KNN - 1] = ~0ull;
            }
            if (tx == 0)
                pl[(rowg * 7 + mc) * KNN + r] = g;
        }
    }
}

// ---------------- K3b: merge 7 sorted partial lists -> final idx ----------------
__global__ __launch_bounds__(256) void k3b_merge(
    const unsigned long long* __restrict__ pl, int* __restrict__ idxout)
{
    int r = blockIdx.x * 256 + threadIdx.x;   // 12544 rows
    const unsigned long long* base = pl + (size_t)r * 63;
    unsigned long long list[KNN];
    #pragma unroll
    for (int q = 0; q < KNN; ++q) list[q] = ~0ull;
    for (int c = 0; c < 63; ++c) {
        unsigned long long k = base[c];
        if (k < list[KNN - 1]) {
            list[KNN - 1] = k;
            #pragma unroll
            for (int q = KNN - 1; q > 0; --q) {
                unsigned long long lo = list[q - 1], hi = list[q];
                if (hi < lo) { list[q - 1] = hi; list[q] = lo; }
            }
        }
    }
    #pragma unroll
    for (int q = 0; q < KNN; ++q)
        idxout[(size_t)r * KNN + q] = (int)(list[q] & 0xffffffffu);
}

// ---------------- K4: g = gelu(bn_g(P + max_k Q[idx[k]])) (in-place into P) ----------------
__global__ __launch_bounds__(384) void k4_agg(
    float* __restrict__ P, const float* __restrict__ Q,
    const int* __restrict__ idx, const float* __restrict__ cst)
{
    int blk = blockIdx.x;
    int b = blk / N_PIX;
    size_t row = (size_t)blk;
    const int* id = idx + row * KNN;
    int o = threadIdx.x;
    const float* Qb = Q + (size_t)b * N_PIX * HID_DIM;
    float v = -INFINITY;
    #pragma unroll
    for (int k = 0; k < KNN; ++k)
        v = fmaxf(v, Qb[(size_t)id[k] * HID_DIM + o]);
    float gp = P[row * HID_DIM + o] + v;
    float y = gp * cst[384 + o] + cst[768 + o];
    float ge = 0.5f * y * (1.0f + erff(y * 0.70710678118654752f));
    P[row * HID_DIM + o] = ge;
}

// ---------------- K5: out = bn2(g @ fc2_w^T + fc2_b) + x ----------------
__global__ __launch_bounds__(256) void k5_fc2_bn2(
    const float* __restrict__ g, const float* __restrict__ w,
    const float* __restrict__ bias, const float* __restrict__ cst,
    const float* __restrict__ x, float* __restrict__ out)
{
    __shared__ float As[32][64];
    __shared__ float Bs[32][64];
    int bx = blockIdx.x;
    int c0 = blockIdx.y * 64;
    int b  = bx / 49;
    int n0 = (bx % 49) * 64;
    int r0 = bx * 64;
    int t = threadIdx.x;
    int tx = t & 15, ty = t >> 4;
    float acc[4][4] = {};
    for (int kc = 0; kc < 12; ++kc) {
        #pragma unroll
        for (int p = 0; p < 2; ++p) {
            int idx = t + p * 256;
            int j = idx >> 3, c4 = idx & 7;
            float4 v = *reinterpret_cast<const float4*>(g + (size_t)(r0 + j) * HID_DIM + kc * 32 + c4 * 4);
            As[c4 * 4 + 0][j] = v.x; As[c4 * 4 + 1][j] = v.y;
            As[c4 * 4 + 2][j] = v.z; As[c4 * 4 + 3][j] = v.w;
        }
        #pragma unroll
        for (int p = 0; p < 2; ++p) {
            int idx = t + p * 256;
            int oo = idx >> 3, c4 = idx & 7;
            float4 v = *reinterpret_cast<const float4*>(w + (size_t)(c0 + oo) * HID_DIM + kc * 32 + c4 * 4);
            Bs[c4 * 4 + 0][oo] = v.x; Bs[c4 * 4 + 1][oo] = v.y;
            Bs[c4 * 4 + 2][oo] = v.z; Bs[c4 * 4 + 3][oo] = v.w;
        }
        __syncthreads();
        #pragma unroll
        for (int kk = 0; kk < 32; ++kk) {
            float4 av = *reinterpret_cast<const float4*>(&As[kk][ty * 4]);
            float4 bv = *reinterpret_cast<const float4*>(&Bs[kk][tx * 4]);
            float a[4] = {av.x, av.y, av.z, av.w};
            float bb[4] = {bv.x, bv.y, bv.z, bv.w};
            #pragma unroll
            for (int i = 0; i < 4; ++i)
                #pragma unroll
                for (int j = 0; j < 4; ++j) acc[i][j] += a[i] * bb[j];
        }
        __syncthreads();
    }
    #pragma unroll
    for (int i = 0; i < 4; ++i) {
        int n = n0 + ty * 4 + i;
        #pragma unroll
        for (int j = 0; j < 4; ++j) {
            int c = c0 + tx * 4 + j;
            size_t a = (size_t)b * C_DIM * N_PIX + (size_t)c * N_PIX + n;
            float y = (acc[i][j] + bias[c]) * cst[1152 + c] + cst[1344 + c] + x[a];
            out[a] = y;
        }
    }
}

extern "C" void kernel_launch(void* const* d_in, const int* in_sizes, int n_in,
                              void* d_out, int out_size, void* d_ws, size_t ws_size,
                              hipStream_t stream)
{
    const float* x      = (const float*)d_in[0];
    const float* fc1_w  = (const float*)d_in[1];
    const float* fc1_b  = (const float*)d_in[2];
    const float* bn1_g  = (const float*)d_in[3];
    const float* bn1_b  = (const float*)d_in[4];
    const float* bn1_m  = (const float*)d_in[5];
    const float* bn1_v  = (const float*)d_in[6];
    const float* gcn_w  = (const float*)d_in[7];
    const float* gcn_b  = (const float*)d_in[8];
    const float* bng_g  = (const float*)d_in[9];
    const float* bng_b  = (const float*)d_in[10];
    const float* bng_m  = (const float*)d_in[11];
    const float* bng_v  = (const float*)d_in[12];
    const float* fc2_w  = (const float*)d_in[13];
    const float* fc2_b  = (const float*)d_in[14];
    const float* bn2_g  = (const float*)d_in[15];
    const float* bn2_b  = (const float*)d_in[16];
    const float* bn2_m  = (const float*)d_in[17];
    const float* bn2_v  = (const float*)d_in[18];
    float* out = (float*)d_out;

    float* ws  = (float*)d_ws;
    float* h   = ws + OFF_H;
    float* sq  = ws + OFF_SQ;
    float* P   = ws + OFF_P;
    float* Q   = ws + OFF_Q;
    float* wc  = ws + OFF_WC;
    float* cst = ws + OFF_CST;
    int*   idx = (int*)(ws + OFF_IDX);
    unsigned long long* pl = (unsigned long long*)(ws + OFF_PL);

    k_prep<<<579, 256, 0, stream>>>(gcn_w, bn1_g, bn1_b, bn1_m, bn1_v,
                                    bng_g, bng_b, bng_m, bng_v,
                                    bn2_g, bn2_b, bn2_m, bn2_v, wc, cst);
    k1_fc1_bn1<<<dim3(196, 3), 256, 0, stream>>>(x, fc1_w, fc1_b, cst, h);
    k_sq<<<49, 256, 0, stream>>>(h, sq);
    k2_pq<<<dim3(196, 12), 256, 0, stream>>>(h, wc, gcn_b, P, Q);
    k3_knn<<<1372, 256, 0, stream>>>(h, sq, pl);
    k3b_merge<<<49, 256, 0, stream>>>(pl, idx);
    k4_agg<<<12544, 384, 0, stream>>>(P, Q, idx, cst);
    k5_fc2_bn2<<<dim3(196, 3), 256, 0, stream>>>(P, fc2_w, fc2_b, cst, x, out);
}

// Round 5
// 464.438 us; speedup vs baseline: 8.9026x; 1.9274x over previous
//
#include <hip/hip_runtime.h>
#include <math.h>

#define N_PIX 3136
#define C_DIM 192
#define HID_DIM 384
#define BATCH 4
#define KNN 9
#define EPS_BN 1e-5f

typedef __attribute__((ext_vector_type(4))) float f32x4;
typedef __attribute__((ext_vector_type(8))) short s16x8;
typedef unsigned short u16;

// ---------------- workspace layout (float elements) ----------------
static const size_t OFF_H   = 0;
static const size_t OFF_SQ  = OFF_H  + (size_t)12544 * 192;
static const size_t OFF_P   = OFF_SQ + 12544;
static const size_t OFF_Q   = OFF_P  + (size_t)12544 * 384;
static const size_t OFF_WC  = OFF_Q  + (size_t)12544 * 384;
static const size_t OFF_CST = OFF_WC + (size_t)768 * 192;
static const size_t OFF_IDX = OFF_CST + 1536;            // int region (12544*9)
static const size_t OFF_PL  = OFF_IDX + 112896;          // u64 region (12544*7*9)
// h2 (bf16 hi|lo, 12544 x 384 u16 = 9.6MB) overlays the P region; k2 runs after k3.

__device__ inline u16 f2bf_rn(float x) {
    unsigned u = __float_as_uint(x);
    unsigned r = u + 0x7fffu + ((u >> 16) & 1u);
    return (u16)(r >> 16);
}

// ---------------- prep: Wcomb + BN scale/shift ----------------
__global__ void k_prep(const float* __restrict__ gcn_w,
                       const float* __restrict__ bn1_g, const float* __restrict__ bn1_b,
                       const float* __restrict__ bn1_m, const float* __restrict__ bn1_v,
                       const float* __restrict__ bng_g, const float* __restrict__ bng_b,
                       const float* __restrict__ bng_m, const float* __restrict__ bng_v,
                       const float* __restrict__ bn2_g, const float* __restrict__ bn2_b,
                       const float* __restrict__ bn2_m, const float* __restrict__ bn2_v,
                       float* __restrict__ wc, float* __restrict__ cst)
{
    int t = blockIdx.x * 256 + threadIdx.x;
    if (t < 768 * 192) {
        int o = t / 192, c = t % 192;
        float v;
        if (o < 384) v = gcn_w[o * 384 + c] - gcn_w[o * 384 + 192 + c];
        else         v = gcn_w[(o - 384) * 384 + 192 + c];
        wc[t] = v;
    }
    int u = t - 768 * 192;
    if (u >= 0 && u < 768) {
        if (u < 192) {
            float s = bn1_g[u] / sqrtf(bn1_v[u] + EPS_BN);
            cst[u] = s; cst[192 + u] = bn1_b[u] - bn1_m[u] * s;
        } else if (u < 576) {
            int ch = u - 192;
            float s = bng_g[ch] / sqrtf(bng_v[ch] + EPS_BN);
            cst[384 + ch] = s; cst[768 + ch] = bng_b[ch] - bng_m[ch] * s;
        } else {
            int ch = u - 576;
            float s = bn2_g[ch] / sqrtf(bn2_v[ch] + EPS_BN);
            cst[1152 + ch] = s; cst[1344 + ch] = bn2_b[ch] - bn2_m[ch] * s;
        }
    }
}

// ---------------- K1: h = bn1(xf @ fc1_w^T + fc1_b) ----------------
__global__ __launch_bounds__(256) void k1_fc1_bn1(
    const float* __restrict__ x, const float* __restrict__ w,
    const float* __restrict__ bias, const float* __restrict__ cst,
    float* __restrict__ h)
{
    __shared__ float As[32][64];
    __shared__ float Bs[32][64];
    int bx = blockIdx.x;
    int o0 = blockIdx.y * 64;
    int b  = bx / 49;
    int n0 = (bx % 49) * 64;
    const float* xb = x + (size_t)b * C_DIM * N_PIX;
    int t = threadIdx.x;
    int tx = t & 15, ty = t >> 4;
    float acc[4][4] = {};
    for (int kc = 0; kc < 6; ++kc) {
        #pragma unroll
        for (int p = 0; p < 2; ++p) {
            int idx = t + p * 256;
            int kk = idx >> 4, j4 = idx & 15;
            float4 v = *reinterpret_cast<const float4*>(xb + (size_t)(kc * 32 + kk) * N_PIX + n0 + j4 * 4);
            *reinterpret_cast<float4*>(&As[kk][j4 * 4]) = v;
        }
        #pragma unroll
        for (int p = 0; p < 2; ++p) {
            int idx = t + p * 256;
            int oo = idx >> 3, c4 = idx & 7;
            float4 v = *reinterpret_cast<const float4*>(w + (size_t)(o0 + oo) * C_DIM + kc * 32 + c4 * 4);
            Bs[c4 * 4 + 0][oo] = v.x; Bs[c4 * 4 + 1][oo] = v.y;
            Bs[c4 * 4 + 2][oo] = v.z; Bs[c4 * 4 + 3][oo] = v.w;
        }
        __syncthreads();
        #pragma unroll
        for (int kk = 0; kk < 32; ++kk) {
            float4 av = *reinterpret_cast<const float4*>(&As[kk][ty * 4]);
            float4 bv = *reinterpret_cast<const float4*>(&Bs[kk][tx * 4]);
            float a[4] = {av.x, av.y, av.z, av.w};
            float bb[4] = {bv.x, bv.y, bv.z, bv.w};
            #pragma unroll
            for (int i = 0; i < 4; ++i)
                #pragma unroll
                for (int j = 0; j < 4; ++j) acc[i][j] += a[i] * bb[j];
        }
        __syncthreads();
    }
    #pragma unroll
    for (int i = 0; i < 4; ++i) {
        int n = n0 + ty * 4 + i;
        size_t r = (size_t)b * N_PIX + n;
        float vals[4];
        #pragma unroll
        for (int j = 0; j < 4; ++j) {
            int o = o0 + tx * 4 + j;
            vals[j] = (acc[i][j] + bias[o]) * cst[o] + cst[192 + o];
        }
        *reinterpret_cast<float4*>(h + r * C_DIM + o0 + tx * 4) =
            make_float4(vals[0], vals[1], vals[2], vals[3]);
    }
}

// ---------------- K1b: sq[r] = sum_c h[r][c]^2 ----------------
__global__ __launch_bounds__(256) void k_sq(const float* __restrict__ h, float* __restrict__ sq)
{
    int r = blockIdx.x * 256 + threadIdx.x;
    const float* hr = h + (size_t)r * C_DIM;
    float s = 0.f;
    #pragma unroll
    for (int c = 0; c < C_DIM; c += 4) {
        float4 v = *reinterpret_cast<const float4*>(hr + c);
        s += v.x * v.x + v.y * v.y + v.z * v.z + v.w * v.w;
    }
    sq[r] = s;
}

// ---------------- K1c: split h into bf16 hi|lo pairs ----------------
// h2 row layout: [192 u16 hi | 192 u16 lo], 384 u16 per row.
__global__ __launch_bounds__(256) void k_split(const float* __restrict__ h, u16* __restrict__ h2)
{
    int t = blockIdx.x * 256 + threadIdx.x;   // 602112 threads, 4 elems each
    int base = t * 4;
    int r = base / C_DIM, c = base % C_DIM;
    float4 v = *reinterpret_cast<const float4*>(h + base);
    float f[4] = {v.x, v.y, v.z, v.w};
    u16 hi[4], lo[4];
    #pragma unroll
    for (int j = 0; j < 4; ++j) {
        hi[j] = f2bf_rn(f[j]);
        float hf = __uint_as_float((unsigned)hi[j] << 16);
        lo[j] = f2bf_rn(f[j] - hf);
    }
    u16* dst = h2 + (size_t)r * 384 + c;
    dst[0] = hi[0]; dst[1] = hi[1]; dst[2] = hi[2]; dst[3] = hi[3];
    dst[192] = lo[0]; dst[193] = lo[1]; dst[194] = lo[2]; dst[195] = lo[3];
}

// ---------------- K2: P = h@Wd^T + gcn_b ; Q = h@W2^T ----------------
__global__ __launch_bounds__(256) void k2_pq(
    const float* __restrict__ h, const float* __restrict__ wc,
    const float* __restrict__ gcnb, float* __restrict__ P, float* __restrict__ Q)
{
    __shared__ float As[32][64];
    __shared__ float Bs[32][64];
    int r0 = blockIdx.x * 64;
    int o0 = blockIdx.y * 64;
    int t = threadIdx.x;
    int tx = t & 15, ty = t >> 4;
    float acc[4][4] = {};
    for (int kc = 0; kc < 6; ++kc) {
        #pragma unroll
        for (int p = 0; p < 2; ++p) {
            int idx = t + p * 256;
            int j = idx >> 3, c4 = idx & 7;
            float4 v = *reinterpret_cast<const float4*>(h + (size_t)(r0 + j) * C_DIM + kc * 32 + c4 * 4);
            As[c4 * 4 + 0][j] = v.x; As[c4 * 4 + 1][j] = v.y;
            As[c4 * 4 + 2][j] = v.z; As[c4 * 4 + 3][j] = v.w;
        }
        #pragma unroll
        for (int p = 0; p < 2; ++p) {
            int idx = t + p * 256;
            int oo = idx >> 3, c4 = idx & 7;
            float4 v = *reinterpret_cast<const float4*>(wc + (size_t)(o0 + oo) * C_DIM + kc * 32 + c4 * 4);
            Bs[c4 * 4 + 0][oo] = v.x; Bs[c4 * 4 + 1][oo] = v.y;
            Bs[c4 * 4 + 2][oo] = v.z; Bs[c4 * 4 + 3][oo] = v.w;
        }
        __syncthreads();
        #pragma unroll
        for (int kk = 0; kk < 32; ++kk) {
            float4 av = *reinterpret_cast<const float4*>(&As[kk][ty * 4]);
            float4 bv = *reinterpret_cast<const float4*>(&Bs[kk][tx * 4]);
            float a[4] = {av.x, av.y, av.z, av.w};
            float bb[4] = {bv.x, bv.y, bv.z, bv.w};
            #pragma unroll
            for (int i = 0; i < 4; ++i)
                #pragma unroll
                for (int j = 0; j < 4; ++j) acc[i][j] += a[i] * bb[j];
        }
        __syncthreads();
    }
    bool isP = (o0 < HID_DIM);
    #pragma unroll
    for (int i = 0; i < 4; ++i) {
        size_t r = (size_t)(r0 + ty * 4 + i);
        int ocb = o0 + tx * 4;
        float vals[4];
        #pragma unroll
        for (int j = 0; j < 4; ++j)
            vals[j] = acc[i][j] + (isP ? gcnb[ocb + j] : 0.0f);
        float4 vv = make_float4(vals[0], vals[1], vals[2], vals[3]);
        if (isP) *reinterpret_cast<float4*>(P + r * HID_DIM + ocb) = vv;
        else     *reinterpret_cast<float4*>(Q + r * HID_DIM + (ocb - HID_DIM)) = vv;
    }
}

// ---------------- K3: MFMA split-bf16 pairwise-dist + partial top-9 ----------------
// grid: 4b * 49strip * 7mchunk = 1372 blocks, 256 threads (4 waves).
// Wave w owns n-rows n0+16w..+15 with A fragments (full K, hi+lo) in registers.
// B tile (64 m-rows) LDS-staged, row stride 392 u16 = 784B (196 dwords == 4 mod 32 -> 2-way, free).
// dot = Ahi*Bhi + Ahi*Blo + Alo*Bhi via mfma_f32_16x16x32_bf16 (fp32 acc).
#define B_STRIDE 392
__global__ __launch_bounds__(256) void k3_knn(
    const u16* __restrict__ h2, const float* __restrict__ sq,
    unsigned long long* __restrict__ pl)
{
    __shared__ u16 Bs[64 * B_STRIDE];   // 50176 B
    int bx    = blockIdx.x;
    int b     = bx / 343;               // 343 = 49*7
    int rem   = bx % 343;
    int strip = rem / 7;
    int mc    = rem % 7;
    int n0 = strip * 64;
    const u16*  hb  = h2 + (size_t)b * N_PIX * 384;
    const float* sqb = sq + (size_t)b * N_PIX;
    int t = threadIdx.x;
    int lane = t & 63, w = t >> 6;
    int col16 = lane & 15, g = lane >> 4;

    // A fragments: row = n0 + 16w + col16, k = ko*32 + g*8 + j
    s16x8 a_hi[6], a_lo[6];
    {
        const u16* ar = hb + (size_t)(n0 + w * 16 + col16) * 384;
        #pragma unroll
        for (int ko = 0; ko < 6; ++ko) {
            a_hi[ko] = *reinterpret_cast<const s16x8*>(ar + ko * 32 + g * 8);
            a_lo[ko] = *reinterpret_cast<const s16x8*>(ar + 192 + ko * 32 + g * 8);
        }
    }

    // candidate rows owned by this lane: n0 + 16w + 4g + i
    unsigned long long cand[4][KNN];
    #pragma unroll
    for (int i = 0; i < 4; ++i)
        #pragma unroll
        for (int q = 0; q < KNN; ++q) cand[i][q] = ~0ull;
    float sqn[4];
    #pragma unroll
    for (int i = 0; i < 4; ++i) sqn[i] = sqb[n0 + w * 16 + g * 4 + i];

    for (int step = 0; step < 7; ++step) {
        int m0 = mc * 448 + step * 64;
        __syncthreads();
        {   // stage 64 m-rows x 384 u16
            int row = t >> 2, part = t & 3;
            const u16* src = hb + (size_t)(m0 + row) * 384 + part * 8;
            u16* dst = Bs + row * B_STRIDE + part * 8;
            #pragma unroll
            for (int c = 0; c < 12; ++c)
                *reinterpret_cast<s16x8*>(dst + c * 32) =
                    *reinterpret_cast<const s16x8*>(src + c * 32);
        }
        __syncthreads();

        f32x4 acc[4];
        #pragma unroll
        for (int mq = 0; mq < 4; ++mq) acc[mq] = (f32x4){0.f, 0.f, 0.f, 0.f};
        #pragma unroll
        for (int ko = 0; ko < 6; ++ko) {
            #pragma unroll
            for (int mq = 0; mq < 4; ++mq) {
                const u16* bp = Bs + (mq * 16 + col16) * B_STRIDE + ko * 32 + g * 8;
                s16x8 bhi = *reinterpret_cast<const s16x8*>(bp);
                s16x8 blo = *reinterpret_cast<const s16x8*>(bp + 192);
                acc[mq] = __builtin_amdgcn_mfma_f32_16x16x32_bf16(a_hi[ko], bhi, acc[mq], 0, 0, 0);
                acc[mq] = __builtin_amdgcn_mfma_f32_16x16x32_bf16(a_hi[ko], blo, acc[mq], 0, 0, 0);
                acc[mq] = __builtin_amdgcn_mfma_f32_16x16x32_bf16(a_lo[ko], bhi, acc[mq], 0, 0, 0);
            }
        }

        #pragma unroll
        for (int mq = 0; mq < 4; ++mq) {
            int m = m0 + mq * 16 + col16;
            float sqm = sqb[m];
            #pragma unroll
            for (int i = 0; i < 4; ++i) {
                float dist = (sqn[i] - 2.0f * acc[mq][i]) + sqm;
                unsigned u = __float_as_uint(dist);
                u = (u & 0x80000000u) ? ~u : (u | 0x80000000u);
                unsigned long long key = ((unsigned long long)u << 32) | (unsigned)m;
                if (key < cand[i][KNN - 1]) {
                    cand[i][KNN - 1] = key;
                    #pragma unroll
                    for (int q = KNN - 1; q > 0; --q) {
                        unsigned long long lo = cand[i][q - 1], hi = cand[i][q];
                        if (hi < lo) { cand[i][q - 1] = hi; cand[i][q] = lo; }
                    }
                }
            }
        }
    }

    // merge 16 partial lists per row across lanes g*16..g*16+15 (shfl_xor s<16)
    #pragma unroll
    for (int i = 0; i < 4; ++i) {
        int n = n0 + w * 16 + g * 4 + i;
        size_t rowg = (size_t)b * N_PIX + n;
        for (int r = 0; r < KNN; ++r) {
            unsigned long long my = cand[i][0];
            unsigned long long gm = my;
            #pragma unroll
            for (int s = 1; s < 16; s <<= 1) {
                unsigned long long o = __shfl_xor(gm, s);
                if (o < gm) gm = o;
            }
            if (gm == my) {
                #pragma unroll
                for (int q = 0; q < KNN - 1; ++q) cand[i][q] = cand[i][q + 1];
                cand[i][KNN - 1] = ~0ull;
            }
            if (col16 == 0)
                pl[(rowg * 7 + mc) * KNN + r] = gm;
        }
    }
}

// ---------------- K3b: merge 7 sorted partial lists -> final idx ----------------
__global__ __launch_bounds__(256) void k3b_merge(
    const unsigned long long* __restrict__ pl, int* __restrict__ idxout)
{
    int r = blockIdx.x * 256 + threadIdx.x;   // 12544 rows
    const unsigned long long* base = pl + (size_t)r * 63;
    unsigned long long list[KNN];
    #pragma unroll
    for (int q = 0; q < KNN; ++q) list[q] = ~0ull;
    for (int c = 0; c < 63; ++c) {
        unsigned long long k = base[c];
        if (k < list[KNN - 1]) {
            list[KNN - 1] = k;
            #pragma unroll
            for (int q = KNN - 1; q > 0; --q) {
                unsigned long long lo = list[q - 1], hi = list[q];
                if (hi < lo) { list[q - 1] = hi; list[q] = lo; }
            }
        }
    }
    #pragma unroll
    for (int q = 0; q < KNN; ++q)
        idxout[(size_t)r * KNN + q] = (int)(list[q] & 0xffffffffu);
}

// ---------------- K4: g = gelu(bn_g(P + max_k Q[idx[k]])) (in-place into P) ----------------
__global__ __launch_bounds__(384) void k4_agg(
    float* __restrict__ P, const float* __restrict__ Q,
    const int* __restrict__ idx, const float* __restrict__ cst)
{
    int blk = blockIdx.x;
    int b = blk / N_PIX;
    size_t row = (size_t)blk;
    const int* id = idx + row * KNN;
    int o = threadIdx.x;
    const float* Qb = Q + (size_t)b * N_PIX * HID_DIM;
    float v = -INFINITY;
    #pragma unroll
    for (int k = 0; k < KNN; ++k)
        v = fmaxf(v, Qb[(size_t)id[k] * HID_DIM + o]);
    float gp = P[row * HID_DIM + o] + v;
    float y = gp * cst[384 + o] + cst[768 + o];
    float ge = 0.5f * y * (1.0f + erff(y * 0.70710678118654752f));
    P[row * HID_DIM + o] = ge;
}

// ---------------- K5: out = bn2(g @ fc2_w^T + fc2_b) + x ----------------
__global__ __launch_bounds__(256) void k5_fc2_bn2(
    const float* __restrict__ g, const float* __restrict__ w,
    const float* __restrict__ bias, const float* __restrict__ cst,
    const float* __restrict__ x, float* __restrict__ out)
{
    __shared__ float As[32][64];
    __shared__ float Bs[32][64];
    int bx = blockIdx.x;
    int c0 = blockIdx.y * 64;
    int b  = bx / 49;
    int n0 = (bx % 49) * 64;
    int r0 = bx * 64;
    int t = threadIdx.x;
    int tx = t & 15, ty = t >> 4;
    float acc[4][4] = {};
    for (int kc = 0; kc < 12; ++kc) {
        #pragma unroll
        for (int p = 0; p < 2; ++p) {
            int idx = t + p * 256;
            int j = idx >> 3, c4 = idx & 7;
            float4 v = *reinterpret_cast<const float4*>(g + (size_t)(r0 + j) * HID_DIM + kc * 32 + c4 * 4);
            As[c4 * 4 + 0][j] = v.x; As[c4 * 4 + 1][j] = v.y;
            As[c4 * 4 + 2][j] = v.z; As[c4 * 4 + 3][j] = v.w;
        }
        #pragma unroll
        for (int p = 0; p < 2; ++p) {
            int idx = t + p * 256;
            int oo = idx >> 3, c4 = idx & 7;
            float4 v = *reinterpret_cast<const float4*>(w + (size_t)(c0 + oo) * HID_DIM + kc * 32 + c4 * 4);
            Bs[c4 * 4 + 0][oo] = v.x; Bs[c4 * 4 + 1][oo] = v.y;
            Bs[c4 * 4 + 2][oo] = v.z; Bs[c4 * 4 + 3][oo] = v.w;
        }
        __syncthreads();
        #pragma unroll
        for (int kk = 0; kk < 32; ++kk) {
            float4 av = *reinterpret_cast<const float4*>(&As[kk][ty * 4]);
            float4 bv = *reinterpret_cast<const float4*>(&Bs[kk][tx * 4]);
            float a[4] = {av.x, av.y, av.z, av.w};
            float bb[4] = {bv.x, bv.y, bv.z, bv.w};
            #pragma unroll
            for (int i = 0; i < 4; ++i)
                #pragma unroll
                for (int j = 0; j < 4; ++j) acc[i][j] += a[i] * bb[j];
        }
        __syncthreads();
    }
    #pragma unroll
    for (int i = 0; i < 4; ++i) {
        int n = n0 + ty * 4 + i;
        #pragma unroll
        for (int j = 0; j < 4; ++j) {
            int c = c0 + tx * 4 + j;
            size_t a = (size_t)b * C_DIM * N_PIX + (size_t)c * N_PIX + n;
            float y = (acc[i][j] + bias[c]) * cst[1152 + c] + cst[1344 + c] + x[a];
            out[a] = y;
        }
    }
}

extern "C" void kernel_launch(void* const* d_in, const int* in_sizes, int n_in,
                              void* d_out, int out_size, void* d_ws, size_t ws_size,
                              hipStream_t stream)
{
    const float* x      = (const float*)d_in[0];
    const float* fc1_w  = (const float*)d_in[1];
    const float* fc1_b  = (const float*)d_in[2];
    const float* bn1_g  = (const float*)d_in[3];
    const float* bn1_b  = (const float*)d_in[4];
    const float* bn1_m  = (const float*)d_in[5];
    const float* bn1_v  = (const float*)d_in[6];
    const float* gcn_w  = (const float*)d_in[7];
    const float* gcn_b  = (const float*)d_in[8];
    const float* bng_g  = (const float*)d_in[9];
    const float* bng_b  = (const float*)d_in[10];
    const float* bng_m  = (const float*)d_in[11];
    const float* bng_v  = (const float*)d_in[12];
    const float* fc2_w  = (const float*)d_in[13];
    const float* fc2_b  = (const float*)d_in[14];
    const float* bn2_g  = (const float*)d_in[15];
    const float* bn2_b  = (const float*)d_in[16];
    const float* bn2_m  = (const float*)d_in[17];
    const float* bn2_v  = (const float*)d_in[18];
    float* out = (float*)d_out;

    float* ws  = (float*)d_ws;
    float* h   = ws + OFF_H;
    float* sq  = ws + OFF_SQ;
    float* P   = ws + OFF_P;
    float* Q   = ws + OFF_Q;
    float* wc  = ws + OFF_WC;
    float* cst = ws + OFF_CST;
    int*   idx = (int*)(ws + OFF_IDX);
    unsigned long long* pl = (unsigned long long*)(ws + OFF_PL);
    u16*   h2  = (u16*)(ws + OFF_P);   // overlays P until k2 runs

    k_prep<<<579, 256, 0, stream>>>(gcn_w, bn1_g, bn1_b, bn1_m, bn1_v,
                                    bng_g, bng_b, bng_m, bng_v,
                                    bn2_g, bn2_b, bn2_m, bn2_v, wc, cst);
    k1_fc1_bn1<<<dim3(196, 3), 256, 0, stream>>>(x, fc1_w, fc1_b, cst, h);
    k_sq<<<49, 256, 0, stream>>>(h, sq);
    k_split<<<2352, 256, 0, stream>>>(h, h2);
    k3_knn<<<1372, 256, 0, stream>>>(h2, sq, pl);
    k3b_merge<<<49, 256, 0, stream>>>(pl, idx);
    k2_pq<<<dim3(196, 12), 256, 0, stream>>>(h, wc, gcn_b, P, Q);
    k4_agg<<<12544, 384, 0, stream>>>(P, Q, idx, cst);
    k5_fc2_bn2<<<dim3(196, 3), 256, 0, stream>>>(P, fc2_w, fc2_b, cst, x, out);
}